// Round 5
// baseline (354.904 us; speedup 1.0000x reference)
//
#include <hip/hip_runtime.h>
#include <hip/hip_bf16.h>

#define FIN  128
#define HDIM 256

using bf16 = __hip_bfloat16;
using short8 = __attribute__((ext_vector_type(8))) short;
using u16x8  = __attribute__((ext_vector_type(8))) unsigned short;
using f32x4  = __attribute__((ext_vector_type(4))) float;

static __device__ __forceinline__ unsigned short f2bu(float f) {
    bf16 t = __float2bfloat16(f);
    return *(unsigned short*)&t;
}
static __device__ __forceinline__ float b2f(unsigned short u) {
    return __uint_as_float(((unsigned)u) << 16);
}

// ---------------- CSR build ----------------

__global__ void k_count(const int* __restrict__ dst, int* __restrict__ deg, int E) {
    int e = blockIdx.x * blockDim.x + threadIdx.x;
    if (e < E) atomicAdd(&deg[dst[e]], 1);
}

__global__ void k_blocksum(const int* __restrict__ deg, int* __restrict__ bsum, int N) {
    __shared__ int s[256];
    int t = threadIdx.x;
    int i = blockIdx.x * 256 + t;
    s[t] = (i < N) ? deg[i] : 0;
    __syncthreads();
    for (int off = 128; off > 0; off >>= 1) {
        if (t < off) s[t] += s[t + off];
        __syncthreads();
    }
    if (t == 0) bsum[blockIdx.x] = s[0];
}

__global__ void k_scanb(const int* __restrict__ bsum, int* __restrict__ boff, int NB) {
    __shared__ int s[256];
    int t = threadIdx.x;
    int v = (t < NB) ? bsum[t] : 0;
    s[t] = v;
    __syncthreads();
    for (int off = 1; off < 256; off <<= 1) {
        int u = (t >= off) ? s[t - off] : 0;
        __syncthreads();
        s[t] += u;
        __syncthreads();
    }
    if (t < NB) boff[t] = s[t] - v;
}

__global__ void k_scatter(const int* __restrict__ deg, const int* __restrict__ boff,
                          int* __restrict__ row_ptr, int* __restrict__ cursor,
                          float* __restrict__ dinv, int N, int E) {
    __shared__ int s[256];
    int t = threadIdx.x;
    int i = blockIdx.x * 256 + t;
    int v = (i < N) ? deg[i] : 0;
    s[t] = v;
    __syncthreads();
    for (int off = 1; off < 256; off <<= 1) {
        int u = (t >= off) ? s[t - off] : 0;
        __syncthreads();
        s[t] += u;
        __syncthreads();
    }
    if (i < N) {
        int excl = boff[blockIdx.x] + s[t] - v;
        row_ptr[i] = excl;
        cursor[i]  = excl;
        dinv[i]    = rsqrtf((float)v + 1.0f);
    }
    if (blockIdx.x == 0 && t == 0) row_ptr[N] = E;
}

// fill CSR with src only (coef folded into g = dinv*h rows)
__global__ void k_fill(const int* __restrict__ src, const int* __restrict__ dst,
                       int* __restrict__ cursor, int* __restrict__ csr, int E) {
    int e = blockIdx.x * blockDim.x + threadIdx.x;
    if (e < E) {
        int pos = atomicAdd(&cursor[dst[e]], 1);
        csr[pos] = src[e];
    }
}

// ---------------- both weight transposes in one launch ----------------
// w[K][C] -> wT[C][K] bf16, for W1 (128x256) then W2 (256x256)

__global__ void k_cvt_w(const float* __restrict__ W1, unsigned short* __restrict__ W1T,
                        const float* __restrict__ W2, unsigned short* __restrict__ W2T) {
    int i = blockIdx.x * blockDim.x + threadIdx.x;
    if (i < FIN * HDIM) {
        int k = i / HDIM, c = i % HDIM;
        W1T[c * FIN + k] = f2bu(W1[i]);
    }
    int j = i - FIN * HDIM;
    if (j >= 0 && j < HDIM * HDIM) {
        int k = j / HDIM, c = j % HDIM;
        W2T[c * HDIM + k] = f2bu(W2[j]);
    }
}

// ---------------- GEMM: G[M,256](bf16) = dinv[m] * (A[M,K] * B[K,256]) ----------------
// BT = B^T [256][K] bf16. 64-col B slice staged in LDS; 4 waves x 4 row-tiles;
// A-frags streamed from global (CVT: fp32->bf16 in-reg). C/D: col=lane&15, row=quad*4+reg.
// Epilogue scales row m by dinv[m] (GCN symmetric-norm fold).

template <int K, bool CVT>
__global__ __launch_bounds__(256, 4) void k_gemm(const void* __restrict__ Av,
                                                 const unsigned short* __restrict__ BT,
                                                 const float* __restrict__ dinv,
                                                 unsigned short* __restrict__ C, int M) {
    constexpr int KP = K + 8;
    __shared__ __align__(16) unsigned short Bs[64 * KP];
    int tid = threadIdx.x;
    int wave = tid >> 6, lane = tid & 63;
    int n0 = blockIdx.x * 64;
    int tileBase = blockIdx.y * 16;

    constexpr int CH = 64 * (K / 8);
    for (int c = tid; c < CH; c += 256) {
        int r = c / (K / 8), kk = (c % (K / 8)) * 8;
        *(short8*)&Bs[r * KP + kk] = *(const short8*)(BT + (size_t)(n0 + r) * K + kk);
    }
    __syncthreads();

    int l15 = lane & 15, quad = lane >> 4;

    #pragma unroll
    for (int i = 0; i < 4; ++i) {
        int rt = tileBase + i * 4 + wave;
        if (rt * 16 >= M) continue;
        int m0 = rt * 16;

        short8 af[K / 32];
        if constexpr (CVT) {
            const float* Ap = (const float*)Av + (size_t)(m0 + l15) * K + quad * 8;
            #pragma unroll
            for (int ks = 0; ks < K / 32; ++ks) {
                float4 lo = *(const float4*)(Ap + ks * 32);
                float4 hi = *(const float4*)(Ap + ks * 32 + 4);
                short8 a;
                a[0] = (short)f2bu(lo.x); a[1] = (short)f2bu(lo.y);
                a[2] = (short)f2bu(lo.z); a[3] = (short)f2bu(lo.w);
                a[4] = (short)f2bu(hi.x); a[5] = (short)f2bu(hi.y);
                a[6] = (short)f2bu(hi.z); a[7] = (short)f2bu(hi.w);
                af[ks] = a;
            }
        } else {
            const unsigned short* Ap = (const unsigned short*)Av + (size_t)(m0 + l15) * K + quad * 8;
            #pragma unroll
            for (int ks = 0; ks < K / 32; ++ks)
                af[ks] = *(const short8*)(Ap + ks * 32);
        }

        f32x4 acc0 = {0.f,0.f,0.f,0.f}, acc1 = {0.f,0.f,0.f,0.f};
        f32x4 acc2 = {0.f,0.f,0.f,0.f}, acc3 = {0.f,0.f,0.f,0.f};
        #pragma unroll
        for (int ks = 0; ks < K / 32; ++ks) {
            int kk = ks * 32 + quad * 8;
            short8 b0 = *(const short8*)&Bs[(l15 +  0) * KP + kk];
            short8 b1 = *(const short8*)&Bs[(l15 + 16) * KP + kk];
            short8 b2 = *(const short8*)&Bs[(l15 + 32) * KP + kk];
            short8 b3 = *(const short8*)&Bs[(l15 + 48) * KP + kk];
            acc0 = __builtin_amdgcn_mfma_f32_16x16x32_bf16(af[ks], b0, acc0, 0, 0, 0);
            acc1 = __builtin_amdgcn_mfma_f32_16x16x32_bf16(af[ks], b1, acc1, 0, 0, 0);
            acc2 = __builtin_amdgcn_mfma_f32_16x16x32_bf16(af[ks], b2, acc2, 0, 0, 0);
            acc3 = __builtin_amdgcn_mfma_f32_16x16x32_bf16(af[ks], b3, acc3, 0, 0, 0);
        }

        unsigned short* Cp = C + (size_t)(m0 + quad * 4) * HDIM + n0 + l15;
        #pragma unroll
        for (int r = 0; r < 4; ++r) {
            float ds = dinv[m0 + quad * 4 + r];
            Cp[(size_t)r * HDIM +  0] = f2bu(acc0[r] * ds);
            Cp[(size_t)r * HDIM + 16] = f2bu(acc1[r] * ds);
            Cp[(size_t)r * HDIM + 32] = f2bu(acc2[r] * ds);
            Cp[(size_t)r * HDIM + 48] = f2bu(acc3[r] * ds);
        }
    }
}

// ---------------- Aggregation: one wave per dst node, pair-gather, pure adds ----------------
// g rows are pre-scaled by dinv[src]; out[n] = relu(dinv[n]*(sum g[src] + g[n]) + bias).
// Lanes 0-31 cover the 512B row of edge j, lanes 32-63 of edge j+1 (16B/lane).
// Unroll 16 edges -> 8 gathers in flight per lane. STORE: write bf16 row.
// !STORE: fused column-sum -> block LDS reduce -> atomicAdd into 8 gsum replicas.

template <bool STORE>
__global__ __launch_bounds__(256) void k_agg(const unsigned short* __restrict__ hb,
                                             const float* __restrict__ dinv,
                                             const int* __restrict__ row_ptr,
                                             const int* __restrict__ csr,
                                             const float* __restrict__ bias,
                                             unsigned short* __restrict__ outb,
                                             float* __restrict__ gsum, int N) {
    __shared__ float gs[4][256];
    int wave = threadIdx.x >> 6, lane = threadIdx.x & 63;
    int half = lane >> 5, hl = lane & 31;
    int c0 = hl * 8;
    int n = blockIdx.x * 4 + wave;

    float r[8] = {0.f,0.f,0.f,0.f,0.f,0.f,0.f,0.f};

    if (n < N) {
        float acc[8] = {0.f,0.f,0.f,0.f,0.f,0.f,0.f,0.f};
        int beg = row_ptr[n], end = row_ptr[n + 1];
        int j = beg;
        for (; j + 16 <= end; j += 16) {
            int s0 = csr[j +  0 + half], s1 = csr[j +  2 + half];
            int s2 = csr[j +  4 + half], s3 = csr[j +  6 + half];
            int s4 = csr[j +  8 + half], s5 = csr[j + 10 + half];
            int s6 = csr[j + 12 + half], s7 = csr[j + 14 + half];
            u16x8 v0 = *(const u16x8*)(hb + (size_t)s0 * HDIM + c0);
            u16x8 v1 = *(const u16x8*)(hb + (size_t)s1 * HDIM + c0);
            u16x8 v2 = *(const u16x8*)(hb + (size_t)s2 * HDIM + c0);
            u16x8 v3 = *(const u16x8*)(hb + (size_t)s3 * HDIM + c0);
            u16x8 v4 = *(const u16x8*)(hb + (size_t)s4 * HDIM + c0);
            u16x8 v5 = *(const u16x8*)(hb + (size_t)s5 * HDIM + c0);
            u16x8 v6 = *(const u16x8*)(hb + (size_t)s6 * HDIM + c0);
            u16x8 v7 = *(const u16x8*)(hb + (size_t)s7 * HDIM + c0);
            #pragma unroll
            for (int k = 0; k < 8; ++k) acc[k] += b2f(v0[k]);
            #pragma unroll
            for (int k = 0; k < 8; ++k) acc[k] += b2f(v1[k]);
            #pragma unroll
            for (int k = 0; k < 8; ++k) acc[k] += b2f(v2[k]);
            #pragma unroll
            for (int k = 0; k < 8; ++k) acc[k] += b2f(v3[k]);
            #pragma unroll
            for (int k = 0; k < 8; ++k) acc[k] += b2f(v4[k]);
            #pragma unroll
            for (int k = 0; k < 8; ++k) acc[k] += b2f(v5[k]);
            #pragma unroll
            for (int k = 0; k < 8; ++k) acc[k] += b2f(v6[k]);
            #pragma unroll
            for (int k = 0; k < 8; ++k) acc[k] += b2f(v7[k]);
        }
        for (; j + 2 <= end; j += 2) {
            int s = csr[j + half];
            u16x8 v = *(const u16x8*)(hb + (size_t)s * HDIM + c0);
            #pragma unroll
            for (int k = 0; k < 8; ++k) acc[k] += b2f(v[k]);
        }
        if (j < end && half == 0) {          // odd tail: only half 0 contributes
            int s = csr[j];
            u16x8 v = *(const u16x8*)(hb + (size_t)s * HDIM + c0);
            #pragma unroll
            for (int k = 0; k < 8; ++k) acc[k] += b2f(v[k]);
        }

        // self-loop term: + g[n]
        u16x8 sv = *(const u16x8*)(hb + (size_t)n * HDIM + c0);
        if (half == 0) {
            #pragma unroll
            for (int k = 0; k < 8; ++k) acc[k] += b2f(sv[k]);
        }

        #pragma unroll
        for (int k = 0; k < 8; ++k) acc[k] += __shfl_xor(acc[k], 32, 64);

        float bb[8];
        *(float4*)&bb[0] = *(const float4*)(bias + c0);
        *(float4*)&bb[4] = *(const float4*)(bias + c0 + 4);
        float dn = dinv[n];
        #pragma unroll
        for (int k = 0; k < 8; ++k)
            r[k] = fmaxf(fmaf(dn, acc[k], bb[k]), 0.f);

        if (STORE && half == 0) {
            u16x8 o;
            #pragma unroll
            for (int k = 0; k < 8; ++k) o[k] = f2bu(r[k]);
            *(u16x8*)(outb + (size_t)n * HDIM + c0) = o;
        }
    }

    if constexpr (!STORE) {
        if (half == 0) {
            #pragma unroll
            for (int k = 0; k < 8; ++k) gs[wave][c0 + k] = r[k];   // zeros if n>=N
        }
        __syncthreads();
        int t = threadIdx.x;
        float s = gs[0][t] + gs[1][t] + gs[2][t] + gs[3][t];
        atomicAdd(&gsum[((blockIdx.x & 7) << 8) + t], s);
    }
}

// ---------------- final linear on pooled vector (8 gsum replicas) ----------------

__global__ void k_final(const float* __restrict__ gsum, const float* __restrict__ Wl,
                        const float* __restrict__ bl, float* __restrict__ out, float invN) {
    __shared__ float s0[256], s1[256];
    int c = threadIdx.x;
    float g = 0.f;
    #pragma unroll
    for (int rp = 0; rp < 8; ++rp) g += gsum[rp * 256 + c];
    g *= invN;
    s0[c] = g * Wl[c * 2 + 0];
    s1[c] = g * Wl[c * 2 + 1];
    __syncthreads();
    for (int off = 128; off > 0; off >>= 1) {
        if (c < off) { s0[c] += s0[c + off]; s1[c] += s1[c + off]; }
        __syncthreads();
    }
    if (c == 0) { out[0] = s0[0] + bl[0]; out[1] = s1[0] + bl[1]; }
}

// ---------------- launch ----------------

extern "C" void kernel_launch(void* const* d_in, const int* in_sizes, int n_in,
                              void* d_out, int out_size, void* d_ws, size_t ws_size,
                              hipStream_t stream) {
    const float* x  = (const float*)d_in[0];
    const int*   ei = (const int*)d_in[1];
    const float* W1 = (const float*)d_in[3];
    const float* b1 = (const float*)d_in[4];
    const float* W2 = (const float*)d_in[5];
    const float* b2 = (const float*)d_in[6];
    const float* Wl = (const float*)d_in[7];
    const float* bl = (const float*)d_in[8];
    float* out = (float*)d_out;

    const int N = in_sizes[0] / FIN;   // 50000
    const int E = in_sizes[1] / 2;     // 800000
    const int* src = ei;
    const int* dst = ei + E;
    const int NB = (N + 255) / 256;

    char* ws = (char*)d_ws;
    size_t off = 0;
    auto alloc = [&](size_t bytes) -> void* {
        void* p = ws + off;
        off = (off + bytes + 255) & ~(size_t)255;
        return p;
    };
    int*   deg     = (int*)  alloc((size_t)N * 4);
    float* dinv    = (float*)alloc((size_t)N * 4);
    int*   row_ptr = (int*)  alloc((size_t)(N + 1) * 4);
    int*   cursor  = (int*)  alloc((size_t)N * 4);
    int*   bsum    = (int*)  alloc(256 * 4);
    int*   boff    = (int*)  alloc(256 * 4);
    int*   csr     = (int*)  alloc((size_t)E * 4);
    unsigned short* W1T  = (unsigned short*)alloc((size_t)FIN * HDIM * 2);
    unsigned short* W2T  = (unsigned short*)alloc((size_t)HDIM * HDIM * 2);
    unsigned short* hlin = (unsigned short*)alloc((size_t)N * HDIM * 2);  // g rows (both layers)
    unsigned short* h1b  = (unsigned short*)alloc((size_t)N * HDIM * 2);  // agg1 out
    float* gsum    = (float*)alloc((size_t)8 * HDIM * 4);

    hipMemsetAsync(deg, 0, (size_t)N * 4, stream);
    hipMemsetAsync(gsum, 0, (size_t)8 * HDIM * 4, stream);

    // CSR build (by dst)
    k_count   <<<(E + 255) / 256, 256, 0, stream>>>(dst, deg, E);
    k_blocksum<<<NB, 256, 0, stream>>>(deg, bsum, N);
    k_scanb   <<<1, 256, 0, stream>>>(bsum, boff, NB);
    k_scatter <<<NB, 256, 0, stream>>>(deg, boff, row_ptr, cursor, dinv, N, E);
    k_fill    <<<(E + 255) / 256, 256, 0, stream>>>(src, dst, cursor, csr, E);

    // weight casts (single launch)
    k_cvt_w<<<(FIN * HDIM + HDIM * HDIM + 255) / 256, 256, 0, stream>>>(W1, W1T, W2, W2T);

    const int tiles = (N + 15) / 16;
    dim3 gemm_grid(HDIM / 64, (tiles + 15) / 16);

    // layer 1 (A = x fp32, converted in-register; epilogue scales by dinv)
    k_gemm<FIN, true>  <<<gemm_grid, 256, 0, stream>>>(x, W1T, dinv, hlin, N);
    k_agg<true>        <<<(N + 3) / 4, 256, 0, stream>>>(hlin, dinv, row_ptr, csr, b1, h1b, nullptr, N);

    // layer 2 + fused mean-pool partials
    k_gemm<HDIM, false><<<gemm_grid, 256, 0, stream>>>(h1b, W2T, dinv, hlin, N);
    k_agg<false>       <<<(N + 3) / 4, 256, 0, stream>>>(hlin, dinv, row_ptr, csr, b2, nullptr, gsum, N);

    // final linear
    k_final<<<1, 256, 0, stream>>>(gsum, Wl, bl, out, 1.0f / (float)N);
}

// Round 6
// 312.156 us; speedup vs baseline: 1.1369x; 1.1369x over previous
//
#include <hip/hip_runtime.h>
#include <hip/hip_bf16.h>

#define FIN  128
#define HDIM 256

using bf16 = __hip_bfloat16;
using short8 = __attribute__((ext_vector_type(8))) short;
using u16x8  = __attribute__((ext_vector_type(8))) unsigned short;
using f32x4  = __attribute__((ext_vector_type(4))) float;

static __device__ __forceinline__ unsigned short f2bu(float f) {
    bf16 t = __float2bfloat16(f);
    return *(unsigned short*)&t;
}
static __device__ __forceinline__ float b2f(unsigned short u) {
    return __uint_as_float(((unsigned)u) << 16);
}

// ---------------- CSR build ----------------

__global__ void k_count(const int* __restrict__ dst, int* __restrict__ deg, int E) {
    int e = blockIdx.x * blockDim.x + threadIdx.x;
    if (e < E) atomicAdd(&deg[dst[e]], 1);
}

__global__ void k_blocksum(const int* __restrict__ deg, int* __restrict__ bsum, int N) {
    __shared__ int s[256];
    int t = threadIdx.x;
    int i = blockIdx.x * 256 + t;
    s[t] = (i < N) ? deg[i] : 0;
    __syncthreads();
    for (int off = 128; off > 0; off >>= 1) {
        if (t < off) s[t] += s[t + off];
        __syncthreads();
    }
    if (t == 0) bsum[blockIdx.x] = s[0];
}

__global__ void k_scanb(const int* __restrict__ bsum, int* __restrict__ boff, int NB) {
    __shared__ int s[256];
    int t = threadIdx.x;
    int v = (t < NB) ? bsum[t] : 0;
    s[t] = v;
    __syncthreads();
    for (int off = 1; off < 256; off <<= 1) {
        int u = (t >= off) ? s[t - off] : 0;
        __syncthreads();
        s[t] += u;
        __syncthreads();
    }
    if (t < NB) boff[t] = s[t] - v;
}

__global__ void k_scatter(const int* __restrict__ deg, const int* __restrict__ boff,
                          int* __restrict__ row_ptr, int* __restrict__ cursor,
                          float* __restrict__ dinv, int N, int E) {
    __shared__ int s[256];
    int t = threadIdx.x;
    int i = blockIdx.x * 256 + t;
    int v = (i < N) ? deg[i] : 0;
    s[t] = v;
    __syncthreads();
    for (int off = 1; off < 256; off <<= 1) {
        int u = (t >= off) ? s[t - off] : 0;
        __syncthreads();
        s[t] += u;
        __syncthreads();
    }
    if (i < N) {
        int excl = boff[blockIdx.x] + s[t] - v;
        row_ptr[i] = excl;
        cursor[i]  = excl;
        dinv[i]    = rsqrtf((float)v + 1.0f);
    }
    if (blockIdx.x == 0 && t == 0) row_ptr[N] = E;
}

__global__ void k_fill(const int* __restrict__ src, const int* __restrict__ dst,
                       int* __restrict__ cursor, int* __restrict__ csr, int E) {
    int e = blockIdx.x * blockDim.x + threadIdx.x;
    if (e < E) {
        int pos = atomicAdd(&cursor[dst[e]], 1);
        csr[pos] = src[e];
    }
}

// ---------------- weight transposes (one launch) ----------------

__global__ void k_cvt_w(const float* __restrict__ W1, unsigned short* __restrict__ W1T,
                        const float* __restrict__ W2, unsigned short* __restrict__ W2T) {
    int i = blockIdx.x * blockDim.x + threadIdx.x;
    if (i < FIN * HDIM) {
        int k = i / HDIM, c = i % HDIM;
        W1T[c * FIN + k] = f2bu(W1[i]);
    }
    int j = i - FIN * HDIM;
    if (j >= 0 && j < HDIM * HDIM) {
        int k = j / HDIM, c = j % HDIM;
        W2T[c * HDIM + k] = f2bu(W2[j]);
    }
}

// ---------------- gx = dinv ⊙ x, fp32 -> bf16 (8 elems/thread) ----------------

__global__ void k_gx(const float* __restrict__ x, const float* __restrict__ dinv,
                     unsigned short* __restrict__ gx, int NF) {
    int base = (blockIdx.x * blockDim.x + threadIdx.x) * 8;
    if (base >= NF) return;
    float ds = dinv[base >> 7];              // row = base / 128
    float4 lo = *(const float4*)(x + base);
    float4 hi = *(const float4*)(x + base + 4);
    u16x8 o;
    o[0] = f2bu(lo.x * ds); o[1] = f2bu(lo.y * ds);
    o[2] = f2bu(lo.z * ds); o[3] = f2bu(lo.w * ds);
    o[4] = f2bu(hi.x * ds); o[5] = f2bu(hi.y * ds);
    o[6] = f2bu(hi.z * ds); o[7] = f2bu(hi.w * ds);
    *(u16x8*)(gx + base) = o;
}

// ---------------- agg on 128-dim rows: ax = dinv[n]*(sum gx[src] + gx[n]) ----------------
// Quarter-wave per edge (16 lanes x 16B = 256B row). Unroll 16 edges = 4 gathers
// in flight per lane; 4-edge mid loop; predicated tail.

__global__ __launch_bounds__(256) void k_agg128(const unsigned short* __restrict__ gx,
                                                const float* __restrict__ dinv,
                                                const int* __restrict__ row_ptr,
                                                const int* __restrict__ csr,
                                                unsigned short* __restrict__ outb, int N) {
    int wave = threadIdx.x >> 6, lane = threadIdx.x & 63;
    int quad = lane >> 4, l16 = lane & 15;
    int c0 = l16 * 8;
    int n = blockIdx.x * 4 + wave;
    if (n >= N) return;

    float acc[8] = {0.f,0.f,0.f,0.f,0.f,0.f,0.f,0.f};
    int beg = row_ptr[n], end = row_ptr[n + 1];
    int j = beg;
    for (; j + 16 <= end; j += 16) {
        int s0 = csr[j +  0 + quad], s1 = csr[j +  4 + quad];
        int s2 = csr[j +  8 + quad], s3 = csr[j + 12 + quad];
        u16x8 v0 = *(const u16x8*)(gx + (size_t)s0 * FIN + c0);
        u16x8 v1 = *(const u16x8*)(gx + (size_t)s1 * FIN + c0);
        u16x8 v2 = *(const u16x8*)(gx + (size_t)s2 * FIN + c0);
        u16x8 v3 = *(const u16x8*)(gx + (size_t)s3 * FIN + c0);
        #pragma unroll
        for (int k = 0; k < 8; ++k) acc[k] += b2f(v0[k]);
        #pragma unroll
        for (int k = 0; k < 8; ++k) acc[k] += b2f(v1[k]);
        #pragma unroll
        for (int k = 0; k < 8; ++k) acc[k] += b2f(v2[k]);
        #pragma unroll
        for (int k = 0; k < 8; ++k) acc[k] += b2f(v3[k]);
    }
    for (; j + 4 <= end; j += 4) {
        int s = csr[j + quad];
        u16x8 v = *(const u16x8*)(gx + (size_t)s * FIN + c0);
        #pragma unroll
        for (int k = 0; k < 8; ++k) acc[k] += b2f(v[k]);
    }
    if (j + quad < end) {                    // 0-3 remaining edges
        int s = csr[j + quad];
        u16x8 v = *(const u16x8*)(gx + (size_t)s * FIN + c0);
        #pragma unroll
        for (int k = 0; k < 8; ++k) acc[k] += b2f(v[k]);
    }
    if (quad == 0) {                         // self-loop term
        u16x8 sv = *(const u16x8*)(gx + (size_t)n * FIN + c0);
        #pragma unroll
        for (int k = 0; k < 8; ++k) acc[k] += b2f(sv[k]);
    }
    #pragma unroll
    for (int k = 0; k < 8; ++k) {
        acc[k] += __shfl_xor(acc[k], 16, 64);
        acc[k] += __shfl_xor(acc[k], 32, 64);
    }
    if (quad == 0) {
        float dn = dinv[n];
        u16x8 o;
        #pragma unroll
        for (int k = 0; k < 8; ++k) o[k] = f2bu(dn * acc[k]);
        *(u16x8*)(outb + (size_t)n * FIN + c0) = o;
    }
}

// ---------------- agg on 256-dim rows: a2 = dinv[n]*(sum g2[src] + g2[n]) ----------------
// Half-wave per edge (32 lanes x 16B = 512B row). Unroll 8 edges = 4 gathers in flight.

__global__ __launch_bounds__(256) void k_agg256(const unsigned short* __restrict__ g2,
                                                const float* __restrict__ dinv,
                                                const int* __restrict__ row_ptr,
                                                const int* __restrict__ csr,
                                                unsigned short* __restrict__ outb, int N) {
    int wave = threadIdx.x >> 6, lane = threadIdx.x & 63;
    int half = lane >> 5, hl = lane & 31;
    int c0 = hl * 8;
    int n = blockIdx.x * 4 + wave;
    if (n >= N) return;

    float acc[8] = {0.f,0.f,0.f,0.f,0.f,0.f,0.f,0.f};
    int beg = row_ptr[n], end = row_ptr[n + 1];
    int j = beg;
    for (; j + 8 <= end; j += 8) {
        int s0 = csr[j + 0 + half], s1 = csr[j + 2 + half];
        int s2 = csr[j + 4 + half], s3 = csr[j + 6 + half];
        u16x8 v0 = *(const u16x8*)(g2 + (size_t)s0 * HDIM + c0);
        u16x8 v1 = *(const u16x8*)(g2 + (size_t)s1 * HDIM + c0);
        u16x8 v2 = *(const u16x8*)(g2 + (size_t)s2 * HDIM + c0);
        u16x8 v3 = *(const u16x8*)(g2 + (size_t)s3 * HDIM + c0);
        #pragma unroll
        for (int k = 0; k < 8; ++k) acc[k] += b2f(v0[k]);
        #pragma unroll
        for (int k = 0; k < 8; ++k) acc[k] += b2f(v1[k]);
        #pragma unroll
        for (int k = 0; k < 8; ++k) acc[k] += b2f(v2[k]);
        #pragma unroll
        for (int k = 0; k < 8; ++k) acc[k] += b2f(v3[k]);
    }
    for (; j + 2 <= end; j += 2) {
        int s = csr[j + half];
        u16x8 v = *(const u16x8*)(g2 + (size_t)s * HDIM + c0);
        #pragma unroll
        for (int k = 0; k < 8; ++k) acc[k] += b2f(v[k]);
    }
    if (j < end && half == 0) {
        int s = csr[j];
        u16x8 v = *(const u16x8*)(g2 + (size_t)s * HDIM + c0);
        #pragma unroll
        for (int k = 0; k < 8; ++k) acc[k] += b2f(v[k]);
    }
    if (half == 0) {                         // self-loop term
        u16x8 sv = *(const u16x8*)(g2 + (size_t)n * HDIM + c0);
        #pragma unroll
        for (int k = 0; k < 8; ++k) acc[k] += b2f(sv[k]);
    }
    #pragma unroll
    for (int k = 0; k < 8; ++k) acc[k] += __shfl_xor(acc[k], 32, 64);
    if (half == 0) {
        float dn = dinv[n];
        u16x8 o;
        #pragma unroll
        for (int k = 0; k < 8; ++k) o[k] = f2bu(dn * acc[k]);
        *(u16x8*)(outb + (size_t)n * HDIM + c0) = o;
    }
}

// ---------------- GEMM: relu(A[M,K]*B[K,256] + bias), two epilogues ----------------
// BT = B^T [256][K] bf16, 64-col slice staged in LDS; 4 waves x 4 row-tiles.
// C/D layout: col=lane&15, row=quad*4+reg.
// POOL=false: store g = dinv[row] * relu(acc+bias) as bf16 rows.
// POOL=true : no store; column-sums of relu(acc+bias) -> LDS -> 8 gsum replicas.

template <int K, bool POOL>
__global__ __launch_bounds__(256, 4) void k_gemm(const unsigned short* __restrict__ A,
                                                 const unsigned short* __restrict__ BT,
                                                 const float* __restrict__ bias,
                                                 const float* __restrict__ dinv,
                                                 unsigned short* __restrict__ C,
                                                 float* __restrict__ gsum, int M) {
    constexpr int KP = K + 8;
    __shared__ __align__(16) unsigned short Bs[64 * KP];
    __shared__ float gs[4][64];
    int tid = threadIdx.x;
    int wave = tid >> 6, lane = tid & 63;
    int n0 = blockIdx.x * 64;
    int tileBase = blockIdx.y * 16;

    constexpr int CH = 64 * (K / 8);
    for (int c = tid; c < CH; c += 256) {
        int r = c / (K / 8), kk = (c % (K / 8)) * 8;
        *(short8*)&Bs[r * KP + kk] = *(const short8*)(BT + (size_t)(n0 + r) * K + kk);
    }
    __syncthreads();

    int l15 = lane & 15, quad = lane >> 4;
    float sb0 = bias[n0 + l15], sb1 = bias[n0 + 16 + l15];
    float sb2 = bias[n0 + 32 + l15], sb3 = bias[n0 + 48 + l15];
    float cs0 = 0.f, cs1 = 0.f, cs2 = 0.f, cs3 = 0.f;

    #pragma unroll
    for (int i = 0; i < 4; ++i) {
        int rt = tileBase + i * 4 + wave;
        if (rt * 16 >= M) continue;
        int m0 = rt * 16;

        short8 af[K / 32];
        const unsigned short* Ap = A + (size_t)(m0 + l15) * K + quad * 8;
        #pragma unroll
        for (int ks = 0; ks < K / 32; ++ks)
            af[ks] = *(const short8*)(Ap + ks * 32);

        f32x4 acc0 = {0.f,0.f,0.f,0.f}, acc1 = {0.f,0.f,0.f,0.f};
        f32x4 acc2 = {0.f,0.f,0.f,0.f}, acc3 = {0.f,0.f,0.f,0.f};
        #pragma unroll
        for (int ks = 0; ks < K / 32; ++ks) {
            int kk = ks * 32 + quad * 8;
            short8 b0 = *(const short8*)&Bs[(l15 +  0) * KP + kk];
            short8 b1 = *(const short8*)&Bs[(l15 + 16) * KP + kk];
            short8 b2 = *(const short8*)&Bs[(l15 + 32) * KP + kk];
            short8 b3 = *(const short8*)&Bs[(l15 + 48) * KP + kk];
            acc0 = __builtin_amdgcn_mfma_f32_16x16x32_bf16(af[ks], b0, acc0, 0, 0, 0);
            acc1 = __builtin_amdgcn_mfma_f32_16x16x32_bf16(af[ks], b1, acc1, 0, 0, 0);
            acc2 = __builtin_amdgcn_mfma_f32_16x16x32_bf16(af[ks], b2, acc2, 0, 0, 0);
            acc3 = __builtin_amdgcn_mfma_f32_16x16x32_bf16(af[ks], b3, acc3, 0, 0, 0);
        }

        if constexpr (!POOL) {
            unsigned short* Cp = C + (size_t)(m0 + quad * 4) * HDIM + n0 + l15;
            #pragma unroll
            for (int r = 0; r < 4; ++r) {
                float ds = dinv[m0 + quad * 4 + r];
                Cp[(size_t)r * HDIM +  0] = f2bu(fmaxf(acc0[r] + sb0, 0.f) * ds);
                Cp[(size_t)r * HDIM + 16] = f2bu(fmaxf(acc1[r] + sb1, 0.f) * ds);
                Cp[(size_t)r * HDIM + 32] = f2bu(fmaxf(acc2[r] + sb2, 0.f) * ds);
                Cp[(size_t)r * HDIM + 48] = f2bu(fmaxf(acc3[r] + sb3, 0.f) * ds);
            }
        } else {
            #pragma unroll
            for (int r = 0; r < 4; ++r) {
                cs0 += fmaxf(acc0[r] + sb0, 0.f);
                cs1 += fmaxf(acc1[r] + sb1, 0.f);
                cs2 += fmaxf(acc2[r] + sb2, 0.f);
                cs3 += fmaxf(acc3[r] + sb3, 0.f);
            }
        }
    }

    if constexpr (POOL) {
        cs0 += __shfl_xor(cs0, 16, 64); cs0 += __shfl_xor(cs0, 32, 64);
        cs1 += __shfl_xor(cs1, 16, 64); cs1 += __shfl_xor(cs1, 32, 64);
        cs2 += __shfl_xor(cs2, 16, 64); cs2 += __shfl_xor(cs2, 32, 64);
        cs3 += __shfl_xor(cs3, 16, 64); cs3 += __shfl_xor(cs3, 32, 64);
        if (quad == 0) {
            gs[wave][l15 +  0] = cs0;
            gs[wave][l15 + 16] = cs1;
            gs[wave][l15 + 32] = cs2;
            gs[wave][l15 + 48] = cs3;
        }
        __syncthreads();
        if (tid < 64) {
            float s = gs[0][tid] + gs[1][tid] + gs[2][tid] + gs[3][tid];
            atomicAdd(&gsum[((blockIdx.y & 7) << 8) + n0 + tid], s);
        }
    }
}

// ---------------- final linear on pooled vector (8 gsum replicas) ----------------

__global__ void k_final(const float* __restrict__ gsum, const float* __restrict__ Wl,
                        const float* __restrict__ bl, float* __restrict__ out, float invN) {
    __shared__ float s0[256], s1[256];
    int c = threadIdx.x;
    float g = 0.f;
    #pragma unroll
    for (int rp = 0; rp < 8; ++rp) g += gsum[rp * 256 + c];
    g *= invN;
    s0[c] = g * Wl[c * 2 + 0];
    s1[c] = g * Wl[c * 2 + 1];
    __syncthreads();
    for (int off = 128; off > 0; off >>= 1) {
        if (c < off) { s0[c] += s0[c + off]; s1[c] += s1[c + off]; }
        __syncthreads();
    }
    if (c == 0) { out[0] = s0[0] + bl[0]; out[1] = s1[0] + bl[1]; }
}

// ---------------- launch ----------------

extern "C" void kernel_launch(void* const* d_in, const int* in_sizes, int n_in,
                              void* d_out, int out_size, void* d_ws, size_t ws_size,
                              hipStream_t stream) {
    const float* x  = (const float*)d_in[0];
    const int*   ei = (const int*)d_in[1];
    const float* W1 = (const float*)d_in[3];
    const float* b1 = (const float*)d_in[4];
    const float* W2 = (const float*)d_in[5];
    const float* b2 = (const float*)d_in[6];
    const float* Wl = (const float*)d_in[7];
    const float* bl = (const float*)d_in[8];
    float* out = (float*)d_out;

    const int N = in_sizes[0] / FIN;   // 50000
    const int E = in_sizes[1] / 2;     // 800000
    const int* src = ei;
    const int* dst = ei + E;
    const int NB = (N + 255) / 256;

    char* ws = (char*)d_ws;
    size_t off = 0;
    auto alloc = [&](size_t bytes) -> void* {
        void* p = ws + off;
        off = (off + bytes + 255) & ~(size_t)255;
        return p;
    };
    int*   deg     = (int*)  alloc((size_t)N * 4);
    float* dinv    = (float*)alloc((size_t)N * 4);
    int*   row_ptr = (int*)  alloc((size_t)(N + 1) * 4);
    int*   cursor  = (int*)  alloc((size_t)N * 4);
    int*   bsum    = (int*)  alloc(256 * 4);
    int*   boff    = (int*)  alloc(256 * 4);
    int*   csr     = (int*)  alloc((size_t)E * 4);
    unsigned short* W1T = (unsigned short*)alloc((size_t)FIN * HDIM * 2);
    unsigned short* W2T = (unsigned short*)alloc((size_t)HDIM * HDIM * 2);
    unsigned short* gx  = (unsigned short*)alloc((size_t)N * FIN * 2);   // dinv*x bf16
    unsigned short* ax  = (unsigned short*)alloc((size_t)N * FIN * 2);   // agg1 out
    unsigned short* g2  = (unsigned short*)alloc((size_t)N * HDIM * 2);  // dinv*h1 bf16
    unsigned short* a2  = (unsigned short*)alloc((size_t)N * HDIM * 2);  // agg2 out
    float* gsum    = (float*)alloc((size_t)8 * HDIM * 4);

    hipMemsetAsync(deg, 0, (size_t)N * 4, stream);
    hipMemsetAsync(gsum, 0, (size_t)8 * HDIM * 4, stream);

    // CSR build (by dst)
    k_count   <<<(E + 255) / 256, 256, 0, stream>>>(dst, deg, E);
    k_blocksum<<<NB, 256, 0, stream>>>(deg, bsum, N);
    k_scanb   <<<1, 256, 0, stream>>>(bsum, boff, NB);
    k_scatter <<<NB, 256, 0, stream>>>(deg, boff, row_ptr, cursor, dinv, N, E);
    k_fill    <<<(E + 255) / 256, 256, 0, stream>>>(src, dst, cursor, csr, E);

    // weight casts
    k_cvt_w<<<(FIN * HDIM + HDIM * HDIM + 255) / 256, 256, 0, stream>>>(W1, W1T, W2, W2T);

    // gx = dinv * x (bf16)
    k_gx<<<((size_t)N * FIN / 8 + 255) / 256, 256, 0, stream>>>(x, dinv, gx, N * FIN);

    const int tiles = (N + 15) / 16;
    dim3 gemm_grid(HDIM / 64, (tiles + 15) / 16);

    // layer 1: agg on 128-dim, then GEMM (epilogue: bias+relu+dinv -> g2)
    k_agg128<<<(N + 3) / 4, 256, 0, stream>>>(gx, dinv, row_ptr, csr, ax, N);
    k_gemm<FIN, false><<<gemm_grid, 256, 0, stream>>>(ax, W1T, b1, dinv, g2, nullptr, N);

    // layer 2: agg on 256-dim, then GEMM (epilogue: bias+relu+fused colsum, no store)
    k_agg256<<<(N + 3) / 4, 256, 0, stream>>>(g2, dinv, row_ptr, csr, a2, N);
    k_gemm<HDIM, true><<<gemm_grid, 256, 0, stream>>>(a2, W2T, b2, nullptr, nullptr, gsum, N);

    // final linear
    k_final<<<1, 256, 0, stream>>>(gsum, Wl, bl, out, 1.0f / (float)N);
}

// Round 7
// 296.837 us; speedup vs baseline: 1.1956x; 1.0516x over previous
//
#include <hip/hip_runtime.h>
#include <hip/hip_bf16.h>

#define FIN  128
#define HDIM 256

using bf16 = __hip_bfloat16;
using short8 = __attribute__((ext_vector_type(8))) short;
using u16x8  = __attribute__((ext_vector_type(8))) unsigned short;
using f32x4  = __attribute__((ext_vector_type(4))) float;

static __device__ __forceinline__ unsigned short f2bu(float f) {
    bf16 t = __float2bfloat16(f);
    return *(unsigned short*)&t;
}
static __device__ __forceinline__ float b2f(unsigned short u) {
    return __uint_as_float(((unsigned)u) << 16);
}

// ---------------- k_pre: deg histogram + weight transposes (one launch) ----------------

__global__ void k_pre(const int* __restrict__ dst, int* __restrict__ deg,
                      const float* __restrict__ W1, unsigned short* __restrict__ W1T,
                      const float* __restrict__ W2, unsigned short* __restrict__ W2T,
                      int E, int CB) {
    int b = blockIdx.x;
    if (b < CB) {
        int e = b * 256 + threadIdx.x;
        if (e < E) atomicAdd(&deg[dst[e]], 1);
    } else {
        int i = (b - CB) * 256 + threadIdx.x;
        if (i < FIN * HDIM) {
            int k = i / HDIM, c = i % HDIM;
            W1T[c * FIN + k] = f2bu(W1[i]);
        }
        int j = i - FIN * HDIM;
        if (j >= 0 && j < HDIM * HDIM) {
            int k = j / HDIM, c = j % HDIM;
            W2T[c * HDIM + k] = f2bu(W2[j]);
        }
    }
}

// ---------------- per-block sums of deg ----------------

__global__ void k_blocksum(const int* __restrict__ deg, int* __restrict__ bsum, int N) {
    __shared__ int s[256];
    int t = threadIdx.x;
    int i = blockIdx.x * 256 + t;
    s[t] = (i < N) ? deg[i] : 0;
    __syncthreads();
    for (int off = 128; off > 0; off >>= 1) {
        if (t < off) s[t] += s[t + off];
        __syncthreads();
    }
    if (t == 0) bsum[blockIdx.x] = s[0];
}

// ---------------- k_scanscatter: every block scans bsum redundantly (no cross-block
// sync), then scatters its 256-chunk of row_ptr/cursor/dinv. Block 1 zeroes gsum. ----

__global__ void k_scanscatter(const int* __restrict__ deg, const int* __restrict__ bsum,
                              int* __restrict__ row_ptr, int* __restrict__ cursor,
                              float* __restrict__ dinv, float* __restrict__ gsum,
                              int N, int E, int NB) {
    __shared__ int sb[256];
    __shared__ int s[256];
    int t = threadIdx.x, b = blockIdx.x;
    sb[t] = (t < NB) ? bsum[t] : 0;
    __syncthreads();
    for (int off = 1; off < 256; off <<= 1) {
        int u = (t >= off) ? sb[t - off] : 0;
        __syncthreads();
        sb[t] += u;
        __syncthreads();
    }
    int boffb = (b > 0) ? sb[b - 1] : 0;

    int i = b * 256 + t;
    int v = (i < N) ? deg[i] : 0;
    s[t] = v;
    __syncthreads();
    for (int off = 1; off < 256; off <<= 1) {
        int u = (t >= off) ? s[t - off] : 0;
        __syncthreads();
        s[t] += u;
        __syncthreads();
    }
    if (i < N) {
        int excl = boffb + s[t] - v;
        row_ptr[i] = excl;
        cursor[i]  = excl;
        dinv[i]    = rsqrtf((float)v + 1.0f);
    }
    if (b == 0 && t == 0) row_ptr[N] = E;
    if (b == 1) {
        for (int k = t; k < 8 * HDIM; k += 256) gsum[k] = 0.f;
    }
}

// ---------------- k_postfill: CSR fill + gx = dinv⊙x bf16 (one launch) ----------------

__global__ void k_postfill(const int* __restrict__ src, const int* __restrict__ dst,
                           int* __restrict__ cursor, int* __restrict__ csr,
                           const float* __restrict__ x, const float* __restrict__ dinv,
                           unsigned short* __restrict__ gx, int E, int NF, int FB) {
    int b = blockIdx.x;
    if (b < FB) {
        int e = b * 256 + threadIdx.x;
        if (e < E) {
            int pos = atomicAdd(&cursor[dst[e]], 1);
            csr[pos] = src[e];
        }
    } else {
        int base = ((b - FB) * 256 + threadIdx.x) * 8;
        if (base < NF) {
            float ds = dinv[base >> 7];
            float4 lo = *(const float4*)(x + base);
            float4 hi = *(const float4*)(x + base + 4);
            u16x8 o;
            o[0] = f2bu(lo.x * ds); o[1] = f2bu(lo.y * ds);
            o[2] = f2bu(lo.z * ds); o[3] = f2bu(lo.w * ds);
            o[4] = f2bu(hi.x * ds); o[5] = f2bu(hi.y * ds);
            o[6] = f2bu(hi.z * ds); o[7] = f2bu(hi.w * ds);
            *(u16x8*)(gx + base) = o;
        }
    }
}

// ---------------- agg 128-dim: ax = dinv[n]*(sum gx[src] + gx[n]) ----------------
// Quarter-wave per edge (16 lanes x 16B). Main: 16-edge batches (4 loads in flight).
// Tail: ONE masked 16-slot batch (clamped indices, 0/1 fma weights).

__global__ __launch_bounds__(256) void k_agg128(const unsigned short* __restrict__ gx,
                                                const float* __restrict__ dinv,
                                                const int* __restrict__ row_ptr,
                                                const int* __restrict__ csr,
                                                unsigned short* __restrict__ outb, int N) {
    int wave = threadIdx.x >> 6, lane = threadIdx.x & 63;
    int quad = lane >> 4, l16 = lane & 15;
    int c0 = l16 * 8;
    int n = blockIdx.x * 4 + wave;
    if (n >= N) return;

    float acc[8] = {0.f,0.f,0.f,0.f,0.f,0.f,0.f,0.f};
    int beg = row_ptr[n], end = row_ptr[n + 1];
    int j = beg;
    for (; j + 16 <= end; j += 16) {
        int s0 = csr[j +  0 + quad], s1 = csr[j +  4 + quad];
        int s2 = csr[j +  8 + quad], s3 = csr[j + 12 + quad];
        u16x8 v0 = *(const u16x8*)(gx + (size_t)s0 * FIN + c0);
        u16x8 v1 = *(const u16x8*)(gx + (size_t)s1 * FIN + c0);
        u16x8 v2 = *(const u16x8*)(gx + (size_t)s2 * FIN + c0);
        u16x8 v3 = *(const u16x8*)(gx + (size_t)s3 * FIN + c0);
        #pragma unroll
        for (int k = 0; k < 8; ++k) acc[k] += b2f(v0[k]);
        #pragma unroll
        for (int k = 0; k < 8; ++k) acc[k] += b2f(v1[k]);
        #pragma unroll
        for (int k = 0; k < 8; ++k) acc[k] += b2f(v2[k]);
        #pragma unroll
        for (int k = 0; k < 8; ++k) acc[k] += b2f(v3[k]);
    }
    if (j < end) {                           // masked final batch, remainder 1..15
        int last = end - 1;
        int i0 = j +  0 + quad, i1 = j +  4 + quad;
        int i2 = j +  8 + quad, i3 = j + 12 + quad;
        int s0 = csr[min(i0, last)], s1 = csr[min(i1, last)];
        int s2 = csr[min(i2, last)], s3 = csr[min(i3, last)];
        float w0 = (i0 < end) ? 1.f : 0.f, w1 = (i1 < end) ? 1.f : 0.f;
        float w2 = (i2 < end) ? 1.f : 0.f, w3 = (i3 < end) ? 1.f : 0.f;
        u16x8 v0 = *(const u16x8*)(gx + (size_t)s0 * FIN + c0);
        u16x8 v1 = *(const u16x8*)(gx + (size_t)s1 * FIN + c0);
        u16x8 v2 = *(const u16x8*)(gx + (size_t)s2 * FIN + c0);
        u16x8 v3 = *(const u16x8*)(gx + (size_t)s3 * FIN + c0);
        #pragma unroll
        for (int k = 0; k < 8; ++k) acc[k] = fmaf(w0, b2f(v0[k]), acc[k]);
        #pragma unroll
        for (int k = 0; k < 8; ++k) acc[k] = fmaf(w1, b2f(v1[k]), acc[k]);
        #pragma unroll
        for (int k = 0; k < 8; ++k) acc[k] = fmaf(w2, b2f(v2[k]), acc[k]);
        #pragma unroll
        for (int k = 0; k < 8; ++k) acc[k] = fmaf(w3, b2f(v3[k]), acc[k]);
    }
    if (quad == 0) {                         // self-loop term
        u16x8 sv = *(const u16x8*)(gx + (size_t)n * FIN + c0);
        #pragma unroll
        for (int k = 0; k < 8; ++k) acc[k] += b2f(sv[k]);
    }
    #pragma unroll
    for (int k = 0; k < 8; ++k) {
        acc[k] += __shfl_xor(acc[k], 16, 64);
        acc[k] += __shfl_xor(acc[k], 32, 64);
    }
    if (quad == 0) {
        float dn = dinv[n];
        u16x8 o;
        #pragma unroll
        for (int k = 0; k < 8; ++k) o[k] = f2bu(dn * acc[k]);
        *(u16x8*)(outb + (size_t)n * FIN + c0) = o;
    }
}

// ---------------- agg 256-dim: a2 = dinv[n]*(sum g2[src] + g2[n]) ----------------
// Half-wave per edge (32 lanes x 16B). Main: 8-edge batches (4 loads in flight).
// Tail: ONE masked 8-slot batch.

__global__ __launch_bounds__(256) void k_agg256(const unsigned short* __restrict__ g2,
                                                const float* __restrict__ dinv,
                                                const int* __restrict__ row_ptr,
                                                const int* __restrict__ csr,
                                                unsigned short* __restrict__ outb, int N) {
    int wave = threadIdx.x >> 6, lane = threadIdx.x & 63;
    int half = lane >> 5, hl = lane & 31;
    int c0 = hl * 8;
    int n = blockIdx.x * 4 + wave;
    if (n >= N) return;

    float acc[8] = {0.f,0.f,0.f,0.f,0.f,0.f,0.f,0.f};
    int beg = row_ptr[n], end = row_ptr[n + 1];
    int j = beg;
    for (; j + 8 <= end; j += 8) {
        int s0 = csr[j + 0 + half], s1 = csr[j + 2 + half];
        int s2 = csr[j + 4 + half], s3 = csr[j + 6 + half];
        u16x8 v0 = *(const u16x8*)(g2 + (size_t)s0 * HDIM + c0);
        u16x8 v1 = *(const u16x8*)(g2 + (size_t)s1 * HDIM + c0);
        u16x8 v2 = *(const u16x8*)(g2 + (size_t)s2 * HDIM + c0);
        u16x8 v3 = *(const u16x8*)(g2 + (size_t)s3 * HDIM + c0);
        #pragma unroll
        for (int k = 0; k < 8; ++k) acc[k] += b2f(v0[k]);
        #pragma unroll
        for (int k = 0; k < 8; ++k) acc[k] += b2f(v1[k]);
        #pragma unroll
        for (int k = 0; k < 8; ++k) acc[k] += b2f(v2[k]);
        #pragma unroll
        for (int k = 0; k < 8; ++k) acc[k] += b2f(v3[k]);
    }
    if (j < end) {                           // masked final batch, remainder 1..7
        int last = end - 1;
        int i0 = j + 0 + half, i1 = j + 2 + half;
        int i2 = j + 4 + half, i3 = j + 6 + half;
        int s0 = csr[min(i0, last)], s1 = csr[min(i1, last)];
        int s2 = csr[min(i2, last)], s3 = csr[min(i3, last)];
        float w0 = (i0 < end) ? 1.f : 0.f, w1 = (i1 < end) ? 1.f : 0.f;
        float w2 = (i2 < end) ? 1.f : 0.f, w3 = (i3 < end) ? 1.f : 0.f;
        u16x8 v0 = *(const u16x8*)(g2 + (size_t)s0 * HDIM + c0);
        u16x8 v1 = *(const u16x8*)(g2 + (size_t)s1 * HDIM + c0);
        u16x8 v2 = *(const u16x8*)(g2 + (size_t)s2 * HDIM + c0);
        u16x8 v3 = *(const u16x8*)(g2 + (size_t)s3 * HDIM + c0);
        #pragma unroll
        for (int k = 0; k < 8; ++k) acc[k] = fmaf(w0, b2f(v0[k]), acc[k]);
        #pragma unroll
        for (int k = 0; k < 8; ++k) acc[k] = fmaf(w1, b2f(v1[k]), acc[k]);
        #pragma unroll
        for (int k = 0; k < 8; ++k) acc[k] = fmaf(w2, b2f(v2[k]), acc[k]);
        #pragma unroll
        for (int k = 0; k < 8; ++k) acc[k] = fmaf(w3, b2f(v3[k]), acc[k]);
    }
    if (half == 0) {                         // self-loop term
        u16x8 sv = *(const u16x8*)(g2 + (size_t)n * HDIM + c0);
        #pragma unroll
        for (int k = 0; k < 8; ++k) acc[k] += b2f(sv[k]);
    }
    #pragma unroll
    for (int k = 0; k < 8; ++k) acc[k] += __shfl_xor(acc[k], 32, 64);
    if (half == 0) {
        float dn = dinv[n];
        u16x8 o;
        #pragma unroll
        for (int k = 0; k < 8; ++k) o[k] = f2bu(dn * acc[k]);
        *(u16x8*)(outb + (size_t)n * HDIM + c0) = o;
    }
}

// ---------------- GEMM: relu(A[M,K]*B[K,256] + bias), two epilogues ----------------
// 8 row-tiles per block (4 waves x 2), 64-col B slice in LDS.
// POOL=false: store g = dinv[row]*relu(acc+bias) bf16. POOL=true: fused column-sum.

template <int K, bool POOL>
__global__ __launch_bounds__(256, 4) void k_gemm(const unsigned short* __restrict__ A,
                                                 const unsigned short* __restrict__ BT,
                                                 const float* __restrict__ bias,
                                                 const float* __restrict__ dinv,
                                                 unsigned short* __restrict__ C,
                                                 float* __restrict__ gsum, int M) {
    constexpr int KP = K + 8;
    __shared__ __align__(16) unsigned short Bs[64 * KP];
    __shared__ float gs[4][64];
    int tid = threadIdx.x;
    int wave = tid >> 6, lane = tid & 63;
    int n0 = blockIdx.x * 64;
    int tileBase = blockIdx.y * 8;

    constexpr int CH = 64 * (K / 8);
    for (int c = tid; c < CH; c += 256) {
        int r = c / (K / 8), kk = (c % (K / 8)) * 8;
        *(short8*)&Bs[r * KP + kk] = *(const short8*)(BT + (size_t)(n0 + r) * K + kk);
    }
    __syncthreads();

    int l15 = lane & 15, quad = lane >> 4;
    float sb0 = bias[n0 + l15], sb1 = bias[n0 + 16 + l15];
    float sb2 = bias[n0 + 32 + l15], sb3 = bias[n0 + 48 + l15];
    float cs0 = 0.f, cs1 = 0.f, cs2 = 0.f, cs3 = 0.f;

    #pragma unroll
    for (int i = 0; i < 2; ++i) {
        int rt = tileBase + i * 4 + wave;
        if (rt * 16 >= M) continue;
        int m0 = rt * 16;

        short8 af[K / 32];
        const unsigned short* Ap = A + (size_t)(m0 + l15) * K + quad * 8;
        #pragma unroll
        for (int ks = 0; ks < K / 32; ++ks)
            af[ks] = *(const short8*)(Ap + ks * 32);

        f32x4 acc0 = {0.f,0.f,0.f,0.f}, acc1 = {0.f,0.f,0.f,0.f};
        f32x4 acc2 = {0.f,0.f,0.f,0.f}, acc3 = {0.f,0.f,0.f,0.f};
        #pragma unroll
        for (int ks = 0; ks < K / 32; ++ks) {
            int kk = ks * 32 + quad * 8;
            short8 b0 = *(const short8*)&Bs[(l15 +  0) * KP + kk];
            short8 b1 = *(const short8*)&Bs[(l15 + 16) * KP + kk];
            short8 b2 = *(const short8*)&Bs[(l15 + 32) * KP + kk];
            short8 b3 = *(const short8*)&Bs[(l15 + 48) * KP + kk];
            acc0 = __builtin_amdgcn_mfma_f32_16x16x32_bf16(af[ks], b0, acc0, 0, 0, 0);
            acc1 = __builtin_amdgcn_mfma_f32_16x16x32_bf16(af[ks], b1, acc1, 0, 0, 0);
            acc2 = __builtin_amdgcn_mfma_f32_16x16x32_bf16(af[ks], b2, acc2, 0, 0, 0);
            acc3 = __builtin_amdgcn_mfma_f32_16x16x32_bf16(af[ks], b3, acc3, 0, 0, 0);
        }

        if constexpr (!POOL) {
            unsigned short* Cp = C + (size_t)(m0 + quad * 4) * HDIM + n0 + l15;
            #pragma unroll
            for (int r = 0; r < 4; ++r) {
                float ds = dinv[m0 + quad * 4 + r];
                Cp[(size_t)r * HDIM +  0] = f2bu(fmaxf(acc0[r] + sb0, 0.f) * ds);
                Cp[(size_t)r * HDIM + 16] = f2bu(fmaxf(acc1[r] + sb1, 0.f) * ds);
                Cp[(size_t)r * HDIM + 32] = f2bu(fmaxf(acc2[r] + sb2, 0.f) * ds);
                Cp[(size_t)r * HDIM + 48] = f2bu(fmaxf(acc3[r] + sb3, 0.f) * ds);
            }
        } else {
            #pragma unroll
            for (int r = 0; r < 4; ++r) {
                cs0 += fmaxf(acc0[r] + sb0, 0.f);
                cs1 += fmaxf(acc1[r] + sb1, 0.f);
                cs2 += fmaxf(acc2[r] + sb2, 0.f);
                cs3 += fmaxf(acc3[r] + sb3, 0.f);
            }
        }
    }

    if constexpr (POOL) {
        cs0 += __shfl_xor(cs0, 16, 64); cs0 += __shfl_xor(cs0, 32, 64);
        cs1 += __shfl_xor(cs1, 16, 64); cs1 += __shfl_xor(cs1, 32, 64);
        cs2 += __shfl_xor(cs2, 16, 64); cs2 += __shfl_xor(cs2, 32, 64);
        cs3 += __shfl_xor(cs3, 16, 64); cs3 += __shfl_xor(cs3, 32, 64);
        if (quad == 0) {
            gs[wave][l15 +  0] = cs0;
            gs[wave][l15 + 16] = cs1;
            gs[wave][l15 + 32] = cs2;
            gs[wave][l15 + 48] = cs3;
        }
        __syncthreads();
        if (tid < 64) {
            float s = gs[0][tid] + gs[1][tid] + gs[2][tid] + gs[3][tid];
            atomicAdd(&gsum[((blockIdx.y & 7) << 8) + n0 + tid], s);
        }
    }
}

// ---------------- final linear on pooled vector (8 gsum replicas) ----------------

__global__ void k_final(const float* __restrict__ gsum, const float* __restrict__ Wl,
                        const float* __restrict__ bl, float* __restrict__ out, float invN) {
    __shared__ float s0[256], s1[256];
    int c = threadIdx.x;
    float g = 0.f;
    #pragma unroll
    for (int rp = 0; rp < 8; ++rp) g += gsum[rp * 256 + c];
    g *= invN;
    s0[c] = g * Wl[c * 2 + 0];
    s1[c] = g * Wl[c * 2 + 1];
    __syncthreads();
    for (int off = 128; off > 0; off >>= 1) {
        if (c < off) { s0[c] += s0[c + off]; s1[c] += s1[c + off]; }
        __syncthreads();
    }
    if (c == 0) { out[0] = s0[0] + bl[0]; out[1] = s1[0] + bl[1]; }
}

// ---------------- launch ----------------

extern "C" void kernel_launch(void* const* d_in, const int* in_sizes, int n_in,
                              void* d_out, int out_size, void* d_ws, size_t ws_size,
                              hipStream_t stream) {
    const float* x  = (const float*)d_in[0];
    const int*   ei = (const int*)d_in[1];
    const float* W1 = (const float*)d_in[3];
    const float* b1 = (const float*)d_in[4];
    const float* W2 = (const float*)d_in[5];
    const float* b2 = (const float*)d_in[6];
    const float* Wl = (const float*)d_in[7];
    const float* bl = (const float*)d_in[8];
    float* out = (float*)d_out;

    const int N = in_sizes[0] / FIN;   // 50000
    const int E = in_sizes[1] / 2;     // 800000
    const int* src = ei;
    const int* dst = ei + E;
    const int NB = (N + 255) / 256;    // 196
    const int CB = (E + 255) / 256;    // 3125 (count blocks)
    const int WB = (FIN * HDIM + HDIM * HDIM + 255) / 256;  // 384 (cvt_w blocks)
    const int FB = CB;                 // fill blocks
    const int GB = ((size_t)N * FIN / 8 + 255) / 256;       // 3125 (gx blocks)

    char* ws = (char*)d_ws;
    size_t off = 0;
    auto alloc = [&](size_t bytes) -> void* {
        void* p = ws + off;
        off = (off + bytes + 255) & ~(size_t)255;
        return p;
    };
    int*   deg     = (int*)  alloc((size_t)N * 4);
    float* dinv    = (float*)alloc((size_t)N * 4);
    int*   row_ptr = (int*)  alloc((size_t)(N + 1) * 4);
    int*   cursor  = (int*)  alloc((size_t)N * 4);
    int*   bsum    = (int*)  alloc(256 * 4);
    int*   csr     = (int*)  alloc((size_t)E * 4);
    unsigned short* W1T = (unsigned short*)alloc((size_t)FIN * HDIM * 2);
    unsigned short* W2T = (unsigned short*)alloc((size_t)HDIM * HDIM * 2);
    unsigned short* gx  = (unsigned short*)alloc((size_t)N * FIN * 2);
    unsigned short* ax  = (unsigned short*)alloc((size_t)N * FIN * 2);
    unsigned short* g2  = (unsigned short*)alloc((size_t)N * HDIM * 2);
    unsigned short* a2  = (unsigned short*)alloc((size_t)N * HDIM * 2);
    float* gsum    = (float*)alloc((size_t)8 * HDIM * 4);

    hipMemsetAsync(deg, 0, (size_t)N * 4, stream);

    // counts + weight transposes
    k_pre<<<CB + WB, 256, 0, stream>>>(dst, deg, W1, W1T, W2, W2T, E, CB);
    // block sums, then redundant-scan scatter (also zeroes gsum)
    k_blocksum   <<<NB, 256, 0, stream>>>(deg, bsum, N);
    k_scanscatter<<<NB, 256, 0, stream>>>(deg, bsum, row_ptr, cursor, dinv, gsum, N, E, NB);
    // CSR fill + gx = dinv*x
    k_postfill<<<FB + GB, 256, 0, stream>>>(src, dst, cursor, csr, x, dinv, gx, E, N * FIN, FB);

    const int tiles = (N + 15) / 16;           // 3125
    dim3 gemm_grid(HDIM / 64, (tiles + 7) / 8);

    // layer 1: agg on 128-dim, GEMM (bias+relu+dinv -> g2)
    k_agg128<<<(N + 3) / 4, 256, 0, stream>>>(gx, dinv, row_ptr, csr, ax, N);
    k_gemm<FIN, false><<<gemm_grid, 256, 0, stream>>>(ax, W1T, b1, dinv, g2, nullptr, N);

    // layer 2: agg on 256-dim, GEMM (bias+relu+fused colsum)
    k_agg256<<<(N + 3) / 4, 256, 0, stream>>>(g2, dinv, row_ptr, csr, a2, N);
    k_gemm<HDIM, true><<<gemm_grid, 256, 0, stream>>>(a2, W2T, b2, nullptr, nullptr, gsum, N);

    // final linear
    k_final<<<1, 256, 0, stream>>>(gsum, Wl, bl, out, 1.0f / (float)N);
}